// Round 7
// baseline (320.194 us; speedup 1.0000x reference)
//
#include <hip/hip_runtime.h>
#include <math.h>

#define HD 64
#define KVBLK 64
#define LP 72

typedef __attribute__((ext_vector_type(8))) short short8;
typedef __attribute__((ext_vector_type(4))) short short4v;
typedef __attribute__((ext_vector_type(4))) float f32x4;

__device__ __forceinline__ short f2bf(float f) {
    union { float f; unsigned u; } in;
    in.f = f;
    unsigned r = (in.u + 0x7fff + ((in.u >> 16) & 1)) >> 16;  // RNE
    return (short)r;
}

// ---------------- fp32 -> bf16 convert ----------------
__global__ __launch_bounds__(256) void convert_bf16(const float* __restrict__ in,
                                                    short* __restrict__ out, long n4) {
    long i = blockIdx.x * 256L + threadIdx.x;
    if (i >= n4) return;
    float4 v = reinterpret_cast<const float4*>(in)[i];
    short4v o;
    o[0] = f2bf(v.x); o[1] = f2bf(v.y); o[2] = f2bf(v.z); o[3] = f2bf(v.w);
    reinterpret_cast<short4v*>(out)[i] = o;
}

// ------------- transpose + convert: [K][N] fp32 -> [N][K] bf16 -------------
__global__ __launch_bounds__(256) void transpose_bf16(const float* __restrict__ in,
                                                      short* __restrict__ out, int K, int N) {
    __shared__ float tile[32][33];
    const int n0 = blockIdx.x * 32, k0 = blockIdx.y * 32;
    const int tx = threadIdx.x & 31, ty = threadIdx.x >> 5;
    #pragma unroll
    for (int i = ty; i < 32; i += 8)
        tile[i][tx] = in[(size_t)(k0 + i) * N + n0 + tx];
    __syncthreads();
    #pragma unroll
    for (int i = ty; i < 32; i += 8)
        out[(size_t)(n0 + i) * K + k0 + tx] = f2bf(tile[tx][i]);
}

// ---------------- 256x256 8-phase bf16 GEMM (T2+T3+T4+T5) ----------------
// C[M][N] = A[M][K] @ Bt[N][K]^T + bias. 512 threads = 8 waves (2 Mrows x 4 Ncols).
// Per wave: 128x64 output = acc[8][4] f32x4. BK=64, dbuf by K-tile parity.
// LDS halves [128][64] bf16, XOR-swizzled: byte ^= ((row&7)<<4), both sides (rule 21).
template <typename OutT>
__global__ __launch_bounds__(512, 2) void gemm256(const short* __restrict__ A,
                                                  const short* __restrict__ Bt,
                                                  const float* __restrict__ bias,
                                                  OutT* __restrict__ C,
                                                  int M, int N, int K, int mblocks) {
    __shared__ short As[2][2][128 * 64];
    __shared__ short Bs[2][2][128 * 64];
    const int tid = threadIdx.x;
    const int lane = tid & 63;
    const int w = tid >> 6;
    const int g = lane >> 4, l16 = lane & 15;
    const int wr = w >> 2, wc = w & 3;

    // bijective XCD swizzle (m204), bm-major so one XCD streams one B panel
    const int nwg = gridDim.x;
    const int q = nwg >> 3, r = nwg & 7;
    const int xcd = blockIdx.x & 7, loc = blockIdx.x >> 3;
    const int wgid = (xcd < r ? xcd * (q + 1) : r * (q + 1) + (xcd - r) * q) + loc;
    const int bm = wgid % mblocks, bn = wgid / mblocks;
    const long m0 = (long)bm * 256;
    const int n0 = bn * 256;
    const int NT = K >> 6;

    f32x4 acc[8][4] = {};

    auto stageA = [&](int bufi, int h, int kt) {
        #pragma unroll
        for (int j = 0; j < 2; ++j) {
            const int o = j * 8192 + tid * 16;           // LDS byte offset in half-tile
            const int rw = o >> 7;                        // row 0..127
            const int cb = ((o >> 4) & 7) ^ (rw & 7);     // pre-swizzled source col block
            long gr = m0 + h * 128 + rw; if (gr > M - 1) gr = M - 1;
            const short* src = A + gr * (long)K + kt * 64 + cb * 8;
            __builtin_amdgcn_global_load_lds(
                (const __attribute__((address_space(1))) unsigned*)src,
                (__attribute__((address_space(3))) unsigned*)((char*)&As[bufi][h][0] + o),
                16, 0, 0);
        }
    };
    auto stageB = [&](int bufi, int h, int kt) {
        #pragma unroll
        for (int j = 0; j < 2; ++j) {
            const int o = j * 8192 + tid * 16;
            const int rw = o >> 7;
            const int cb = ((o >> 4) & 7) ^ (rw & 7);
            const short* src = Bt + (size_t)(n0 + h * 128 + rw) * K + kt * 64 + cb * 8;
            __builtin_amdgcn_global_load_lds(
                (const __attribute__((address_space(1))) unsigned*)src,
                (__attribute__((address_space(3))) unsigned*)((char*)&Bs[bufi][h][0] + o),
                16, 0, 0);
        }
    };

    // prologue: tile 0 -> buf 0 (B first, then A: FIFO order matters for vmcnt counts)
    stageB(0, 0, 0); stageB(0, 1, 0);
    stageA(0, 0, 0); stageA(0, 1, 0);
    asm volatile("s_waitcnt vmcnt(4)" ::: "memory");   // B(0) landed, A(0) in flight
    __builtin_amdgcn_s_barrier();

    const char* const Ahb[2] = { (const char*)&As[0][wr][0], (const char*)&As[1][wr][0] };
    const char* const Bhb[2] = { (const char*)&Bs[0][wc >> 1][0], (const char*)&Bs[1][wc >> 1][0] };
    const int brow0 = (wc & 1) * 64;
    const int cxor = (l16 & 7) << 4;

    for (int t = 0; t < NT; ++t) {
        const int cur = t & 1, nxt = cur ^ 1;
        short8 bf[2][4];
        #pragma unroll
        for (int p = 0; p < 4; ++p) {
            if (p == 0) {
                // ds_read all B-frags of tile t (gated by prev-iter P4 vmcnt+barrier)
                #pragma unroll
                for (int ks = 0; ks < 2; ++ks)
                    #pragma unroll
                    for (int ni = 0; ni < 4; ++ni) {
                        const int row = brow0 + ni * 16 + l16;
                        bf[ks][ni] = *(const short8*)(
                            Bhb[cur] + row * 128 + ((ks * 64 + g * 16) ^ cxor));
                    }
                if (t + 1 < NT) {
                    stageB(nxt, 0, t + 1); stageB(nxt, 1, t + 1);
                    asm volatile("s_waitcnt vmcnt(4)" ::: "memory");  // A(t) landed
                } else {
                    asm volatile("s_waitcnt vmcnt(0)" ::: "memory");
                }
                __builtin_amdgcn_s_barrier();
            }
            // A-frags for this phase: mi = 2p, 2p+1
            short8 af[2][2];
            #pragma unroll
            for (int ks = 0; ks < 2; ++ks)
                #pragma unroll
                for (int ml = 0; ml < 2; ++ml) {
                    const int row = (2 * p + ml) * 16 + l16;
                    af[ks][ml] = *(const short8*)(
                        Ahb[cur] + row * 128 + ((ks * 64 + g * 16) ^ cxor));
                }
            if (p == 1 && t + 1 < NT) { stageA(nxt, 0, t + 1); stageA(nxt, 1, t + 1); }
            if (p > 0) __builtin_amdgcn_s_barrier();

            __builtin_amdgcn_s_setprio(1);
            #pragma unroll
            for (int ml = 0; ml < 2; ++ml)
                #pragma unroll
                for (int ks = 0; ks < 2; ++ks)
                    #pragma unroll
                    for (int ni = 0; ni < 4; ++ni)
                        acc[2 * p + ml][ni] = __builtin_amdgcn_mfma_f32_16x16x32_bf16(
                            af[ks][ml], bf[ks][ni], acc[2 * p + ml][ni], 0, 0, 0);
            __builtin_amdgcn_s_setprio(0);

            if (p == 3 && t + 1 < NT)
                asm volatile("s_waitcnt vmcnt(4)" ::: "memory");      // B(t+1) landed
            __builtin_amdgcn_s_barrier();
        }
    }

    // epilogue
    float bv[4];
    #pragma unroll
    for (int ni = 0; ni < 4; ++ni) bv[ni] = bias[n0 + wc * 64 + ni * 16 + l16];
    #pragma unroll
    for (int mi = 0; mi < 8; ++mi) {
        #pragma unroll
        for (int rr = 0; rr < 4; ++rr) {
            const long row = m0 + wr * 128 + mi * 16 + g * 4 + rr;
            if (row < M) {
                #pragma unroll
                for (int ni = 0; ni < 4; ++ni) {
                    float val = acc[mi][ni][rr] + bv[ni];
                    const size_t idx = (size_t)row * N + n0 + wc * 64 + ni * 16 + l16;
                    if constexpr (__is_same(OutT, float)) C[idx] = val;
                    else C[idx] = f2bf(val);
                }
            }
        }
    }
}

// ---------------- flash attention: swapped-QK^T, in-lane softmax (unchanged) ----------------
__global__ __launch_bounds__(256) void flash_attn(const short* __restrict__ qkvb,
                                                  const float* __restrict__ scale,
                                                  short* __restrict__ out) {
    constexpr int Nn = 577, Cc = 768, C3 = 2304, NQB = 10, NH = 12;
    const int bid = blockIdx.x;
    const int swz = (bid & 7) * 480 + (bid >> 3);
    const int q0 = (swz % NQB) * 64;
    const int h  = (swz / NQB) % NH;
    const int b  = swz / (NQB * NH);

    const int tid  = threadIdx.x;
    const int w    = tid >> 6;
    const int lane = tid & 63;
    const int g    = lane >> 4;
    const int l16  = lane & 15;

    __shared__ alignas(16) short Ks[KVBLK * HD];
    __shared__ alignas(16) short Vts[HD][LP];
    __shared__ alignas(16) short Ps[4][16][LP];
    __shared__ float facs[4][16];

    const float sl2 = scale[h] * 1.44269504088896f;
    const short* base = qkvb + (size_t)b * Nn * C3;
    const short* kglob = base + Cc + h * HD;
    const short* vglob = base + 2 * Cc + h * HD;

    const int qrow = q0 + w * 16 + l16;
    const int qr = qrow < Nn ? qrow : Nn - 1;
    const short* qp = base + (size_t)qr * C3 + h * HD;
    short8 aq[2];
    aq[0] = *reinterpret_cast<const short8*>(qp + 8 * g);
    aq[1] = *reinterpret_cast<const short8*>(qp + 32 + 8 * g);

    f32x4 oacc[4] = {};
    float mrun = -INFINITY;
    float lrun = 0.f;

    const int tr = tid >> 2;
    const int tc = (tid & 3) * 16;
    const int kst_row = lane >> 3;
    const int kst_dblk = (lane & 7) ^ (lane >> 3);

    for (int kv0 = 0; kv0 < Nn; kv0 += KVBLK) {
        #pragma unroll
        for (int t = 0; t < 2; ++t) {
            const int i = 2 * w + t;
            int kr = kv0 + 8 * i + kst_row;
            if (kr > Nn - 1) kr = Nn - 1;
            const short* src = kglob + (size_t)kr * C3 + kst_dblk * 8;
            __builtin_amdgcn_global_load_lds(
                (const __attribute__((address_space(1))) unsigned*)src,
                (__attribute__((address_space(3))) unsigned*)&Ks[i * 512],
                16, 0, 0);
        }
        {
            int kr = kv0 + tr; if (kr > Nn - 1) kr = Nn - 1;
            const short* vsrc = vglob + (size_t)kr * C3 + tc;
            short8 v0 = *reinterpret_cast<const short8*>(vsrc);
            short8 v1 = *reinterpret_cast<const short8*>(vsrc + 8);
            #pragma unroll
            for (int i = 0; i < 8; ++i) {
                Vts[tc + i][tr]     = v0[i];
                Vts[tc + 8 + i][tr] = v1[i];
            }
        }
        __syncthreads();

        f32x4 sacc[4] = {};
        #pragma unroll
        for (int f = 0; f < 4; ++f) {
            #pragma unroll
            for (int c = 0; c < 2; ++c) {
                const int slot = (4 * c + g) ^ (l16 & 7);
                short8 ak = *reinterpret_cast<const short8*>(
                    &Ks[(16 * f + l16) * 64 + slot * 8]);
                sacc[f] = __builtin_amdgcn_mfma_f32_16x16x32_bf16(ak, aq[c], sacc[f], 0, 0, 0);
            }
        }

        const int ig = q0 + w * 16 + l16;
        float s2[4][4];
        #pragma unroll
        for (int f = 0; f < 4; ++f) {
            #pragma unroll
            for (int r = 0; r < 4; ++r) {
                const int jg = kv0 + 16 * f + 4 * g + r;
                float s = sacc[f][r] * sl2;
                if (jg >= Nn || (jg == ig && ig >= 1)) s = -INFINITY;
                s2[f][r] = s;
            }
        }

        float mx = s2[0][0];
        #pragma unroll
        for (int f = 0; f < 4; ++f)
            #pragma unroll
            for (int r = 0; r < 4; ++r)
                if (f + r) mx = fmaxf(mx, s2[f][r]);
        mx = fmaxf(mx, __shfl_xor(mx, 16, 64));
        mx = fmaxf(mx, __shfl_xor(mx, 32, 64));
        const float mnew = fmaxf(mrun, mx);
        const float fac = __builtin_amdgcn_exp2f(mrun - mnew);
        mrun = mnew;

        float sum = 0.f;
        #pragma unroll
        for (int f = 0; f < 4; ++f)
            #pragma unroll
            for (int r = 0; r < 4; ++r) {
                float p = __builtin_amdgcn_exp2f(s2[f][r] - mnew);
                s2[f][r] = p;
                sum += p;
            }
        sum += __shfl_xor(sum, 16, 64);
        sum += __shfl_xor(sum, 32, 64);
        lrun = lrun * fac + sum;

        if (lane < 16) facs[w][lane] = fac;
        asm volatile("s_waitcnt lgkmcnt(0)" ::: "memory");
        #pragma unroll
        for (int r = 0; r < 4; ++r) {
            const float fr = facs[w][4 * g + r];
            #pragma unroll
            for (int df = 0; df < 4; ++df) oacc[df][r] *= fr;
        }

        #pragma unroll
        for (int f = 0; f < 4; ++f) {
            short4v pk;
            #pragma unroll
            for (int r = 0; r < 4; ++r) pk[r] = f2bf(s2[f][r]);
            *reinterpret_cast<short4v*>(&Ps[w][l16][16 * f + 4 * g]) = pk;
        }
        asm volatile("s_waitcnt lgkmcnt(0)" ::: "memory");

        #pragma unroll
        for (int c = 0; c < 2; ++c) {
            short8 pa = *reinterpret_cast<const short8*>(&Ps[w][l16][32 * c + 8 * g]);
            #pragma unroll
            for (int df = 0; df < 4; ++df) {
                short8 bv = *reinterpret_cast<const short8*>(&Vts[16 * df + l16][32 * c + 8 * g]);
                oacc[df] = __builtin_amdgcn_mfma_f32_16x16x32_bf16(pa, bv, oacc[df], 0, 0, 0);
            }
        }
        __syncthreads();
    }

    if (lane < 16) facs[w][lane] = lrun;
    asm volatile("s_waitcnt lgkmcnt(0)" ::: "memory");
    #pragma unroll
    for (int r = 0; r < 4; ++r) {
        const int og = q0 + w * 16 + g * 4 + r;
        if (og < Nn) {
            const float inv = 1.f / facs[w][4 * g + r];
            #pragma unroll
            for (int df = 0; df < 4; ++df)
                out[(size_t)(b * Nn + og) * Cc + h * HD + 16 * df + l16] =
                    f2bf(oacc[df][r] * inv);
        }
    }
}

extern "C" void kernel_launch(void* const* d_in, const int* in_sizes, int n_in,
                              void* d_out, int out_size, void* d_ws, size_t ws_size,
                              hipStream_t stream) {
    const float* x      = (const float*)d_in[0];
    const float* w_qkv  = (const float*)d_in[1];
    const float* b_qkv  = (const float*)d_in[2];
    const float* scale  = (const float*)d_in[3];
    const float* w_proj = (const float*)d_in[4];
    const float* b_proj = (const float*)d_in[5];
    float* out = (float*)d_out;

    const int B = 32, N = 577, C = 768, H = 12;
    const int M  = B * N;     // 18464
    const int C3 = 3 * C;     // 2304
    const int MB = (M + 255) / 256;   // 73

    short* qkvb   = (short*)d_ws;
    short* attn_o = qkvb + (size_t)M * C3;
    short* xb     = attn_o + (size_t)M * C;
    short* wqkvT  = xb + (size_t)M * C;
    short* wprojT = wqkvT + (size_t)C3 * C;

    dim3 blk(256);
    const long n4 = (long)M * C / 4;
    convert_bf16<<<dim3((n4 + 255) / 256), blk, 0, stream>>>(x, xb, n4);
    transpose_bf16<<<dim3(C3 / 32, C / 32), blk, 0, stream>>>(w_qkv, wqkvT, C, C3);
    transpose_bf16<<<dim3(C / 32, C / 32), blk, 0, stream>>>(w_proj, wprojT, C, C);

    gemm256<short><<<dim3(MB * (C3 / 256)), dim3(512), 0, stream>>>(
        xb, wqkvT, b_qkv, qkvb, M, C3, C, MB);

    flash_attn<<<dim3(((N + 63) / 64) * H * B), blk, 0, stream>>>(qkvb, scale, attn_o);

    gemm256<float><<<dim3(MB * (C / 256)), dim3(512), 0, stream>>>(
        attn_o, wprojT, b_proj, out, M, C, C, MB);
}

// Round 8
// 300.053 us; speedup vs baseline: 1.0671x; 1.0671x over previous
//
#include <hip/hip_runtime.h>
#include <math.h>

#define HD 64
#define KVBLK 64
#define LP 72

typedef __attribute__((ext_vector_type(8))) short short8;
typedef __attribute__((ext_vector_type(4))) short short4v;
typedef __attribute__((ext_vector_type(4))) float f32x4;

__device__ __forceinline__ short f2bf(float f) {
    union { float f; unsigned u; } in;
    in.f = f;
    unsigned r = (in.u + 0x7fff + ((in.u >> 16) & 1)) >> 16;  // RNE
    return (short)r;
}

// ---------------- fp32 -> bf16 convert ----------------
__global__ __launch_bounds__(256) void convert_bf16(const float* __restrict__ in,
                                                    short* __restrict__ out, long n4) {
    long i = blockIdx.x * 256L + threadIdx.x;
    if (i >= n4) return;
    float4 v = reinterpret_cast<const float4*>(in)[i];
    short4v o;
    o[0] = f2bf(v.x); o[1] = f2bf(v.y); o[2] = f2bf(v.z); o[3] = f2bf(v.w);
    reinterpret_cast<short4v*>(out)[i] = o;
}

// ------------- transpose + convert: [K][N] fp32 -> [N][K] bf16 -------------
__global__ __launch_bounds__(256) void transpose_bf16(const float* __restrict__ in,
                                                      short* __restrict__ out, int K, int N) {
    __shared__ float tile[32][33];
    const int n0 = blockIdx.x * 32, k0 = blockIdx.y * 32;
    const int tx = threadIdx.x & 31, ty = threadIdx.x >> 5;
    #pragma unroll
    for (int i = ty; i < 32; i += 8)
        tile[i][tx] = in[(size_t)(k0 + i) * N + n0 + tx];
    __syncthreads();
    #pragma unroll
    for (int i = ty; i < 32; i += 8)
        out[(size_t)(n0 + i) * K + k0 + tx] = f2bf(tile[tx][i]);
}

// ---------------- bf16 MFMA GEMM (m97 structure, 128x128, XCD-swizzled 1D grid) ----------------
// C[M][N] = A[M][K] bf16 @ Bt[N][K]^T bf16 + bias. Grid: 1D, row-major (bm major),
// bijective XCD swizzle so each XCD owns contiguous row-bands (A reuse in its L2).
template <typename OutT>
__global__ __launch_bounds__(256) void gemm_bf16(const short* __restrict__ A,
                                                 const short* __restrict__ Bt,
                                                 const float* __restrict__ bias,
                                                 OutT* __restrict__ C,
                                                 int M, int N, int K, int nbn) {
    __shared__ short As[128 * 64];
    __shared__ short Bs[128 * 64];
    const int tid = threadIdx.x;
    const int w = tid >> 6, lane = tid & 63;
    const int g = lane >> 4, l16 = lane & 15;

    const int nwg = gridDim.x;
    const int q = nwg >> 3, r = nwg & 7;
    const int xcd = blockIdx.x & 7, loc = blockIdx.x >> 3;
    const int wgid = (xcd < r ? xcd * (q + 1) : r * (q + 1) + (xcd - r) * q) + loc;
    const int bm = wgid / nbn, bn = wgid % nbn;
    const int m0 = bm * 128, n0 = bn * 128;
    const int wm = (w >> 1) * 64, wn = (w & 1) * 64;

    f32x4 acc[4][4] = {};

    const int lr = lane >> 3;
    const int lc = (lane & 7) * 8;

    for (int k0 = 0; k0 < K; k0 += 64) {
        #pragma unroll
        for (int t = 0; t < 4; ++t) {
            const int rr = 32 * w + 8 * t + lr;
            long arow = m0 + rr; if (arow > M - 1) arow = M - 1;
            const short* ga = A + arow * K + k0 + lc;
            const short* gb = Bt + (size_t)(n0 + rr) * K + k0 + lc;
            __builtin_amdgcn_global_load_lds(
                (const __attribute__((address_space(1))) unsigned*)ga,
                (__attribute__((address_space(3))) unsigned*)&As[(32 * w + 8 * t) * 64],
                16, 0, 0);
            __builtin_amdgcn_global_load_lds(
                (const __attribute__((address_space(1))) unsigned*)gb,
                (__attribute__((address_space(3))) unsigned*)&Bs[(32 * w + 8 * t) * 64],
                16, 0, 0);
        }
        __syncthreads();
        #pragma unroll
        for (int ks = 0; ks < 2; ++ks) {
            short8 af[4], bfr[4];
            #pragma unroll
            for (int mi = 0; mi < 4; ++mi)
                af[mi] = *reinterpret_cast<const short8*>(
                    &As[(wm + mi * 16 + l16) * 64 + ks * 32 + g * 8]);
            #pragma unroll
            for (int ni = 0; ni < 4; ++ni)
                bfr[ni] = *reinterpret_cast<const short8*>(
                    &Bs[(wn + ni * 16 + l16) * 64 + ks * 32 + g * 8]);
            #pragma unroll
            for (int mi = 0; mi < 4; ++mi)
                #pragma unroll
                for (int ni = 0; ni < 4; ++ni)
                    acc[mi][ni] = __builtin_amdgcn_mfma_f32_16x16x32_bf16(
                        af[mi], bfr[ni], acc[mi][ni], 0, 0, 0);
        }
        __syncthreads();
    }

    float bv[4];
    #pragma unroll
    for (int ni = 0; ni < 4; ++ni) bv[ni] = bias[n0 + wn + ni * 16 + l16];
    #pragma unroll
    for (int mi = 0; mi < 4; ++mi) {
        #pragma unroll
        for (int rr = 0; rr < 4; ++rr) {
            const int row = m0 + wm + mi * 16 + g * 4 + rr;
            if (row < M) {
                #pragma unroll
                for (int ni = 0; ni < 4; ++ni) {
                    float val = acc[mi][ni][rr] + bv[ni];
                    if constexpr (__is_same(OutT, float))
                        C[(size_t)row * N + n0 + wn + ni * 16 + l16] = val;
                    else
                        C[(size_t)row * N + n0 + wn + ni * 16 + l16] = f2bf(val);
                }
            }
        }
    }
}

// ---------------- flash attention: swapped-QK^T + dbuf pipeline (T14) ----------------
__global__ __launch_bounds__(256) void flash_attn(const short* __restrict__ qkvb,
                                                  const float* __restrict__ scale,
                                                  short* __restrict__ out) {
    constexpr int Nn = 577, Cc = 768, C3 = 2304, NQB = 10, NH = 12;
    constexpr int NT = 10;   // ceil(577/64)
    const int bid = blockIdx.x;
    const int swz = (bid & 7) * 480 + (bid >> 3);   // T1: q-blocks of a (b,h) share an XCD
    const int q0 = (swz % NQB) * 64;
    const int h  = (swz / NQB) % NH;
    const int b  = swz / (NQB * NH);

    const int tid  = threadIdx.x;
    const int w    = tid >> 6;
    const int lane = tid & 63;
    const int g    = lane >> 4;
    const int l16  = lane & 15;

    __shared__ alignas(16) short Ks[2][KVBLK * HD];   // XOR-swizzled content, dbuf
    __shared__ alignas(16) short Vts[2][HD][LP];      // V^T[dim][key], dbuf
    __shared__ alignas(16) short Ps[4][16][LP];       // per-wave P bounce
    __shared__ float facs[4][16];

    const float sl2 = scale[h] * 1.44269504088896f;   // exp2 domain
    const short* base = qkvb + (size_t)b * Nn * C3;
    const short* kglob = base + Cc + h * HD;
    const short* vglob = base + 2 * Cc + h * HD;

    const int qrow = q0 + w * 16 + l16;
    const int qr = qrow < Nn ? qrow : Nn - 1;
    const short* qp = base + (size_t)qr * C3 + h * HD;
    short8 aq[2];
    aq[0] = *reinterpret_cast<const short8*>(qp + 8 * g);
    aq[1] = *reinterpret_cast<const short8*>(qp + 32 + 8 * g);

    f32x4 oacc[4] = {};
    float mrun = -INFINITY, lrun = 0.f;

    const int tr = tid >> 2;
    const int tc = (tid & 3) * 16;
    const int kst_row = lane >> 3;
    const int kst_dblk = (lane & 7) ^ (lane >> 3);

    auto stageK = [&](int bufi, int kv0) {
        #pragma unroll
        for (int t = 0; t < 2; ++t) {
            const int i = 2 * w + t;
            int kr = kv0 + 8 * i + kst_row;
            if (kr > Nn - 1) kr = Nn - 1;
            const short* src = kglob + (size_t)kr * C3 + kst_dblk * 8;
            __builtin_amdgcn_global_load_lds(
                (const __attribute__((address_space(1))) unsigned*)src,
                (__attribute__((address_space(3))) unsigned*)&Ks[bufi][i * 512],
                16, 0, 0);
        }
    };

    short8 vr0, vr1;   // in-flight V regs for next tile
    auto loadV = [&](int kv0) {
        int kr = kv0 + tr; if (kr > Nn - 1) kr = Nn - 1;
        const short* vsrc = vglob + (size_t)kr * C3 + tc;
        vr0 = *reinterpret_cast<const short8*>(vsrc);
        vr1 = *reinterpret_cast<const short8*>(vsrc + 8);
    };
    auto writeV = [&](int bufi) {
        #pragma unroll
        for (int i = 0; i < 8; ++i) {
            Vts[bufi][tc + i][tr]     = vr0[i];
            Vts[bufi][tc + 8 + i][tr] = vr1[i];
        }
    };

    // prologue: stage tile 0
    stageK(0, 0);
    loadV(0);
    asm volatile("s_waitcnt vmcnt(0)" ::: "memory");
    writeV(0);
    __syncthreads();

    for (int t = 0; t < NT; ++t) {
        const int cur = t & 1, nxt = cur ^ 1;
        const int kv0 = t * KVBLK;
        const bool more = (t + 1 < NT);
        if (more) { stageK(nxt, kv0 + KVBLK); loadV(kv0 + KVBLK); }  // issue early

        // ---- S^T = K @ Q^T ----
        f32x4 sacc[4] = {};
        #pragma unroll
        for (int f = 0; f < 4; ++f) {
            #pragma unroll
            for (int c = 0; c < 2; ++c) {
                const int slot = (4 * c + g) ^ (l16 & 7);
                short8 ak = *reinterpret_cast<const short8*>(
                    &Ks[cur][(16 * f + l16) * 64 + slot * 8]);
                sacc[f] = __builtin_amdgcn_mfma_f32_16x16x32_bf16(ak, aq[c], sacc[f], 0, 0, 0);
            }
        }

        // ---- mask + scale; lane owns 16 scores of q-row ig ----
        const int ig = q0 + w * 16 + l16;
        float s2[4][4];
        #pragma unroll
        for (int f = 0; f < 4; ++f)
            #pragma unroll
            for (int r = 0; r < 4; ++r) {
                const int jg = kv0 + 16 * f + 4 * g + r;
                float s = sacc[f][r] * sl2;
                if (jg >= Nn || (jg == ig && ig >= 1)) s = -INFINITY;
                s2[f][r] = s;
            }

        float mx = s2[0][0];
        #pragma unroll
        for (int f = 0; f < 4; ++f)
            #pragma unroll
            for (int r = 0; r < 4; ++r)
                if (f + r) mx = fmaxf(mx, s2[f][r]);
        mx = fmaxf(mx, __shfl_xor(mx, 16, 64));
        mx = fmaxf(mx, __shfl_xor(mx, 32, 64));

        // ---- T13 defer-max: rescale only if some row grew past THR=8 (log2 units) ----
        if (__any(mx > mrun + 8.0f)) {
            const float mnew = fmaxf(mrun, mx);
            const float fac = __builtin_amdgcn_exp2f(mrun - mnew);
            mrun = mnew;
            lrun *= fac;
            if (lane < 16) facs[w][lane] = fac;
            asm volatile("s_waitcnt lgkmcnt(0)" ::: "memory");
            #pragma unroll
            for (int r = 0; r < 4; ++r) {
                const float fr = facs[w][4 * g + r];
                #pragma unroll
                for (int df = 0; df < 4; ++df) oacc[df][r] *= fr;
            }
        }

        float sum = 0.f;
        #pragma unroll
        for (int f = 0; f < 4; ++f)
            #pragma unroll
            for (int r = 0; r < 4; ++r) {
                float p = __builtin_amdgcn_exp2f(s2[f][r] - mrun);
                s2[f][r] = p;
                sum += p;
            }
        sum += __shfl_xor(sum, 16, 64);
        sum += __shfl_xor(sum, 32, 64);
        lrun += sum;

        // ---- P pack via v_cvt_pk_bf16_f32 (2 f32 -> 1 u32) ----
        #pragma unroll
        for (int f = 0; f < 4; ++f) {
            unsigned plo, phi;
            asm("v_cvt_pk_bf16_f32 %0, %1, %2" : "=v"(plo) : "v"(s2[f][0]), "v"(s2[f][1]));
            asm("v_cvt_pk_bf16_f32 %0, %1, %2" : "=v"(phi) : "v"(s2[f][2]), "v"(s2[f][3]));
            unsigned* dst = reinterpret_cast<unsigned*>(&Ps[w][l16][16 * f + 4 * g]);
            dst[0] = plo; dst[1] = phi;
        }
        asm volatile("s_waitcnt lgkmcnt(0)" ::: "memory");

        // ---- drain staging, write next V (readers of cur unaffected) ----
        if (more) {
            asm volatile("s_waitcnt vmcnt(0)" ::: "memory");
            writeV(nxt);
        }

        // ---- O += P @ V ----
        #pragma unroll
        for (int c = 0; c < 2; ++c) {
            short8 pa = *reinterpret_cast<const short8*>(&Ps[w][l16][32 * c + 8 * g]);
            #pragma unroll
            for (int df = 0; df < 4; ++df) {
                short8 bv = *reinterpret_cast<const short8*>(
                    &Vts[cur][16 * df + l16][32 * c + 8 * g]);
                oacc[df] = __builtin_amdgcn_mfma_f32_16x16x32_bf16(pa, bv, oacc[df], 0, 0, 0);
            }
        }
        __syncthreads();   // full drain: K(nxt) landed, V(nxt)/P writes visible
    }

    // ---- epilogue ----
    if (lane < 16) facs[w][lane] = lrun;
    asm volatile("s_waitcnt lgkmcnt(0)" ::: "memory");
    #pragma unroll
    for (int r = 0; r < 4; ++r) {
        const int og = q0 + w * 16 + g * 4 + r;
        if (og < Nn) {
            const float inv = 1.f / facs[w][4 * g + r];
            #pragma unroll
            for (int df = 0; df < 4; ++df)
                out[(size_t)(b * Nn + og) * Cc + h * HD + 16 * df + l16] =
                    f2bf(oacc[df][r] * inv);
        }
    }
}

extern "C" void kernel_launch(void* const* d_in, const int* in_sizes, int n_in,
                              void* d_out, int out_size, void* d_ws, size_t ws_size,
                              hipStream_t stream) {
    const float* x      = (const float*)d_in[0];
    const float* w_qkv  = (const float*)d_in[1];
    const float* b_qkv  = (const float*)d_in[2];
    const float* scale  = (const float*)d_in[3];
    const float* w_proj = (const float*)d_in[4];
    const float* b_proj = (const float*)d_in[5];
    float* out = (float*)d_out;

    const int B = 32, N = 577, C = 768, H = 12;
    const int M  = B * N;     // 18464
    const int C3 = 3 * C;     // 2304
    const int MB = (M + 127) / 128;   // 145

    short* qkvb   = (short*)d_ws;
    short* attn_o = qkvb + (size_t)M * C3;
    short* xb     = attn_o + (size_t)M * C;
    short* wqkvT  = xb + (size_t)M * C;
    short* wprojT = wqkvT + (size_t)C3 * C;

    dim3 blk(256);
    const long n4 = (long)M * C / 4;
    convert_bf16<<<dim3((n4 + 255) / 256), blk, 0, stream>>>(x, xb, n4);
    transpose_bf16<<<dim3(C3 / 32, C / 32), blk, 0, stream>>>(w_qkv, wqkvT, C, C3);
    transpose_bf16<<<dim3(C / 32, C / 32), blk, 0, stream>>>(w_proj, wprojT, C, C);

    gemm_bf16<short><<<dim3(MB * (C3 / 128)), blk, 0, stream>>>(
        xb, wqkvT, b_qkv, qkvb, M, C3, C, C3 / 128);

    flash_attn<<<dim3(((N + 63) / 64) * H * B), blk, 0, stream>>>(qkvb, scale, attn_o);

    gemm_bf16<float><<<dim3(MB * (C / 128)), blk, 0, stream>>>(
        attn_o, wprojT, b_proj, out, M, C, C, C / 128);
}

// Round 9
// 289.540 us; speedup vs baseline: 1.1059x; 1.0363x over previous
//
#include <hip/hip_runtime.h>
#include <math.h>

#define HD 64
#define KVBLK 64
#define LP 72

typedef __attribute__((ext_vector_type(8))) short short8;
typedef __attribute__((ext_vector_type(4))) short short4v;
typedef __attribute__((ext_vector_type(4))) float f32x4;

__device__ __forceinline__ short f2bf(float f) {
    union { float f; unsigned u; } in;
    in.f = f;
    unsigned r = (in.u + 0x7fff + ((in.u >> 16) & 1)) >> 16;  // RNE
    return (short)r;
}

// ---------------- fp32 -> bf16 convert ----------------
__global__ __launch_bounds__(256) void convert_bf16(const float* __restrict__ in,
                                                    short* __restrict__ out, long n4) {
    long i = blockIdx.x * 256L + threadIdx.x;
    if (i >= n4) return;
    float4 v = reinterpret_cast<const float4*>(in)[i];
    short4v o;
    o[0] = f2bf(v.x); o[1] = f2bf(v.y); o[2] = f2bf(v.z); o[3] = f2bf(v.w);
    reinterpret_cast<short4v*>(out)[i] = o;
}

// ------------- transpose + convert: [K][N] fp32 -> [N][K] bf16 -------------
__global__ __launch_bounds__(256) void transpose_bf16(const float* __restrict__ in,
                                                      short* __restrict__ out, int K, int N) {
    __shared__ float tile[32][33];
    const int n0 = blockIdx.x * 32, k0 = blockIdx.y * 32;
    const int tx = threadIdx.x & 31, ty = threadIdx.x >> 5;
    #pragma unroll
    for (int i = ty; i < 32; i += 8)
        tile[i][tx] = in[(size_t)(k0 + i) * N + n0 + tx];
    __syncthreads();
    #pragma unroll
    for (int i = ty; i < 32; i += 8)
        out[(size_t)(n0 + i) * K + k0 + tx] = f2bf(tile[tx][i]);
}

// ------- bf16 MFMA GEMM: 128x128, explicit LDS dbuf, ONE barrier per K-step -------
// Stage tile t+1 at top of step t -> loads fly under compute(t); __syncthreads'
// vmcnt(0) drain at step end is the (1-deep) pipeline boundary.
template <typename OutT>
__global__ __launch_bounds__(256) void gemm_bf16(const short* __restrict__ A,
                                                 const short* __restrict__ Bt,
                                                 const float* __restrict__ bias,
                                                 OutT* __restrict__ C,
                                                 int M, int N, int K, int nbn) {
    __shared__ short As[2][128 * 64];
    __shared__ short Bs[2][128 * 64];
    const int tid = threadIdx.x;
    const int w = tid >> 6, lane = tid & 63;
    const int g = lane >> 4, l16 = lane & 15;

    // bijective XCD swizzle (m204), bm-major: each XCD owns contiguous row-bands
    const int nwg = gridDim.x;
    const int q = nwg >> 3, r = nwg & 7;
    const int xcd = blockIdx.x & 7, loc = blockIdx.x >> 3;
    const int wgid = (xcd < r ? xcd * (q + 1) : r * (q + 1) + (xcd - r) * q) + loc;
    const int bm = wgid / nbn, bn = wgid % nbn;
    const int m0 = bm * 128, n0 = bn * 128;
    const int wm = (w >> 1) * 64, wn = (w & 1) * 64;

    f32x4 acc[4][4] = {};

    const int lr = lane >> 3;
    const int lc = (lane & 7) * 8;
    const int NT = K >> 6;

    auto stage = [&](int buf, int k0) {
        #pragma unroll
        for (int t = 0; t < 4; ++t) {
            const int rr = 32 * w + 8 * t + lr;
            long arow = m0 + rr; if (arow > M - 1) arow = M - 1;
            const short* ga = A + arow * K + k0 + lc;
            const short* gb = Bt + (size_t)(n0 + rr) * K + k0 + lc;
            __builtin_amdgcn_global_load_lds(
                (const __attribute__((address_space(1))) unsigned*)ga,
                (__attribute__((address_space(3))) unsigned*)&As[buf][(32 * w + 8 * t) * 64],
                16, 0, 0);
            __builtin_amdgcn_global_load_lds(
                (const __attribute__((address_space(1))) unsigned*)gb,
                (__attribute__((address_space(3))) unsigned*)&Bs[buf][(32 * w + 8 * t) * 64],
                16, 0, 0);
        }
    };

    stage(0, 0);
    __syncthreads();   // drains prologue stage (vmcnt(0)+lgkmcnt(0)+barrier)

    for (int kt = 0; kt < NT; ++kt) {
        const int cur = kt & 1;
        if (kt + 1 < NT) stage(cur ^ 1, (kt + 1) * 64);   // issue early: fly under MFMA

        #pragma unroll
        for (int ks = 0; ks < 2; ++ks) {
            short8 af[4], bfr[4];
            #pragma unroll
            for (int mi = 0; mi < 4; ++mi)
                af[mi] = *reinterpret_cast<const short8*>(
                    &As[cur][(wm + mi * 16 + l16) * 64 + ks * 32 + g * 8]);
            #pragma unroll
            for (int ni = 0; ni < 4; ++ni)
                bfr[ni] = *reinterpret_cast<const short8*>(
                    &Bs[cur][(wn + ni * 16 + l16) * 64 + ks * 32 + g * 8]);
            __builtin_amdgcn_s_setprio(1);
            #pragma unroll
            for (int mi = 0; mi < 4; ++mi)
                #pragma unroll
                for (int ni = 0; ni < 4; ++ni)
                    acc[mi][ni] = __builtin_amdgcn_mfma_f32_16x16x32_bf16(
                        af[mi], bfr[ni], acc[mi][ni], 0, 0, 0);
            __builtin_amdgcn_s_setprio(0);
        }
        __syncthreads();   // single drain point per K-step
    }

    float bv[4];
    #pragma unroll
    for (int ni = 0; ni < 4; ++ni) bv[ni] = bias[n0 + wn + ni * 16 + l16];
    #pragma unroll
    for (int mi = 0; mi < 4; ++mi) {
        #pragma unroll
        for (int rr = 0; rr < 4; ++rr) {
            const int row = m0 + wm + mi * 16 + g * 4 + rr;
            if (row < M) {
                #pragma unroll
                for (int ni = 0; ni < 4; ++ni) {
                    float val = acc[mi][ni][rr] + bv[ni];
                    if constexpr (__is_same(OutT, float))
                        C[(size_t)row * N + n0 + wn + ni * 16 + l16] = val;
                    else
                        C[(size_t)row * N + n0 + wn + ni * 16 + l16] = f2bf(val);
                }
            }
        }
    }
}

// ---------------- flash attention: swapped-QK^T + dbuf pipeline + setprio ----------------
__global__ __launch_bounds__(256) void flash_attn(const short* __restrict__ qkvb,
                                                  const float* __restrict__ scale,
                                                  short* __restrict__ out) {
    constexpr int Nn = 577, Cc = 768, C3 = 2304, NQB = 10, NH = 12;
    constexpr int NT = 10;
    const int bid = blockIdx.x;
    const int swz = (bid & 7) * 480 + (bid >> 3);
    const int q0 = (swz % NQB) * 64;
    const int h  = (swz / NQB) % NH;
    const int b  = swz / (NQB * NH);

    const int tid  = threadIdx.x;
    const int w    = tid >> 6;
    const int lane = tid & 63;
    const int g    = lane >> 4;
    const int l16  = lane & 15;

    __shared__ alignas(16) short Ks[2][KVBLK * HD];
    __shared__ alignas(16) short Vts[2][HD][LP];
    __shared__ alignas(16) short Ps[4][16][LP];
    __shared__ float facs[4][16];

    const float sl2 = scale[h] * 1.44269504088896f;
    const short* base = qkvb + (size_t)b * Nn * C3;
    const short* kglob = base + Cc + h * HD;
    const short* vglob = base + 2 * Cc + h * HD;

    const int qrow = q0 + w * 16 + l16;
    const int qr = qrow < Nn ? qrow : Nn - 1;
    const short* qp = base + (size_t)qr * C3 + h * HD;
    short8 aq[2];
    aq[0] = *reinterpret_cast<const short8*>(qp + 8 * g);
    aq[1] = *reinterpret_cast<const short8*>(qp + 32 + 8 * g);

    f32x4 oacc[4] = {};
    float mrun = -INFINITY, lrun = 0.f;

    const int tr = tid >> 2;
    const int tc = (tid & 3) * 16;
    const int kst_row = lane >> 3;
    const int kst_dblk = (lane & 7) ^ (lane >> 3);

    auto stageK = [&](int bufi, int kv0) {
        #pragma unroll
        for (int t = 0; t < 2; ++t) {
            const int i = 2 * w + t;
            int kr = kv0 + 8 * i + kst_row;
            if (kr > Nn - 1) kr = Nn - 1;
            const short* src = kglob + (size_t)kr * C3 + kst_dblk * 8;
            __builtin_amdgcn_global_load_lds(
                (const __attribute__((address_space(1))) unsigned*)src,
                (__attribute__((address_space(3))) unsigned*)&Ks[bufi][i * 512],
                16, 0, 0);
        }
    };

    short8 vr0, vr1;
    auto loadV = [&](int kv0) {
        int kr = kv0 + tr; if (kr > Nn - 1) kr = Nn - 1;
        const short* vsrc = vglob + (size_t)kr * C3 + tc;
        vr0 = *reinterpret_cast<const short8*>(vsrc);
        vr1 = *reinterpret_cast<const short8*>(vsrc + 8);
    };
    auto writeV = [&](int bufi) {
        #pragma unroll
        for (int i = 0; i < 8; ++i) {
            Vts[bufi][tc + i][tr]     = vr0[i];
            Vts[bufi][tc + 8 + i][tr] = vr1[i];
        }
    };

    stageK(0, 0);
    loadV(0);
    asm volatile("s_waitcnt vmcnt(0)" ::: "memory");
    writeV(0);
    __syncthreads();

    for (int t = 0; t < NT; ++t) {
        const int cur = t & 1, nxt = cur ^ 1;
        const int kv0 = t * KVBLK;
        const bool more = (t + 1 < NT);
        if (more) { stageK(nxt, kv0 + KVBLK); loadV(kv0 + KVBLK); }

        f32x4 sacc[4] = {};
        __builtin_amdgcn_s_setprio(1);
        #pragma unroll
        for (int f = 0; f < 4; ++f) {
            #pragma unroll
            for (int c = 0; c < 2; ++c) {
                const int slot = (4 * c + g) ^ (l16 & 7);
                short8 ak = *reinterpret_cast<const short8*>(
                    &Ks[cur][(16 * f + l16) * 64 + slot * 8]);
                sacc[f] = __builtin_amdgcn_mfma_f32_16x16x32_bf16(ak, aq[c], sacc[f], 0, 0, 0);
            }
        }
        __builtin_amdgcn_s_setprio(0);

        const int ig = q0 + w * 16 + l16;
        float s2[4][4];
        #pragma unroll
        for (int f = 0; f < 4; ++f)
            #pragma unroll
            for (int r = 0; r < 4; ++r) {
                const int jg = kv0 + 16 * f + 4 * g + r;
                float s = sacc[f][r] * sl2;
                if (jg >= Nn || (jg == ig && ig >= 1)) s = -INFINITY;
                s2[f][r] = s;
            }

        float mx = s2[0][0];
        #pragma unroll
        for (int f = 0; f < 4; ++f)
            #pragma unroll
            for (int r = 0; r < 4; ++r)
                if (f + r) mx = fmaxf(mx, s2[f][r]);
        mx = fmaxf(mx, __shfl_xor(mx, 16, 64));
        mx = fmaxf(mx, __shfl_xor(mx, 32, 64));

        if (__any(mx > mrun + 8.0f)) {
            const float mnew = fmaxf(mrun, mx);
            const float fac = __builtin_amdgcn_exp2f(mrun - mnew);
            mrun = mnew;
            lrun *= fac;
            if (lane < 16) facs[w][lane] = fac;
            asm volatile("s_waitcnt lgkmcnt(0)" ::: "memory");
            #pragma unroll
            for (int r = 0; r < 4; ++r) {
                const float fr = facs[w][4 * g + r];
                #pragma unroll
                for (int df = 0; df < 4; ++df) oacc[df][r] *= fr;
            }
        }

        float sum = 0.f;
        #pragma unroll
        for (int f = 0; f < 4; ++f)
            #pragma unroll
            for (int r = 0; r < 4; ++r) {
                float p = __builtin_amdgcn_exp2f(s2[f][r] - mrun);
                s2[f][r] = p;
                sum += p;
            }
        sum += __shfl_xor(sum, 16, 64);
        sum += __shfl_xor(sum, 32, 64);
        lrun += sum;

        #pragma unroll
        for (int f = 0; f < 4; ++f) {
            unsigned plo, phi;
            asm("v_cvt_pk_bf16_f32 %0, %1, %2" : "=v"(plo) : "v"(s2[f][0]), "v"(s2[f][1]));
            asm("v_cvt_pk_bf16_f32 %0, %1, %2" : "=v"(phi) : "v"(s2[f][2]), "v"(s2[f][3]));
            unsigned* dst = reinterpret_cast<unsigned*>(&Ps[w][l16][16 * f + 4 * g]);
            dst[0] = plo; dst[1] = phi;
        }
        asm volatile("s_waitcnt lgkmcnt(0)" ::: "memory");

        if (more) {
            asm volatile("s_waitcnt vmcnt(0)" ::: "memory");
            writeV(nxt);
        }

        __builtin_amdgcn_s_setprio(1);
        #pragma unroll
        for (int c = 0; c < 2; ++c) {
            short8 pa = *reinterpret_cast<const short8*>(&Ps[w][l16][32 * c + 8 * g]);
            #pragma unroll
            for (int df = 0; df < 4; ++df) {
                short8 bv = *reinterpret_cast<const short8*>(
                    &Vts[cur][16 * df + l16][32 * c + 8 * g]);
                oacc[df] = __builtin_amdgcn_mfma_f32_16x16x32_bf16(pa, bv, oacc[df], 0, 0, 0);
            }
        }
        __builtin_amdgcn_s_setprio(0);
        __syncthreads();
    }

    if (lane < 16) facs[w][lane] = lrun;
    asm volatile("s_waitcnt lgkmcnt(0)" ::: "memory");
    #pragma unroll
    for (int r = 0; r < 4; ++r) {
        const int og = q0 + w * 16 + g * 4 + r;
        if (og < Nn) {
            const float inv = 1.f / facs[w][4 * g + r];
            #pragma unroll
            for (int df = 0; df < 4; ++df)
                out[(size_t)(b * Nn + og) * Cc + h * HD + 16 * df + l16] =
                    f2bf(oacc[df][r] * inv);
        }
    }
}

extern "C" void kernel_launch(void* const* d_in, const int* in_sizes, int n_in,
                              void* d_out, int out_size, void* d_ws, size_t ws_size,
                              hipStream_t stream) {
    const float* x      = (const float*)d_in[0];
    const float* w_qkv  = (const float*)d_in[1];
    const float* b_qkv  = (const float*)d_in[2];
    const float* scale  = (const float*)d_in[3];
    const float* w_proj = (const float*)d_in[4];
    const float* b_proj = (const float*)d_in[5];
    float* out = (float*)d_out;

    const int B = 32, N = 577, C = 768, H = 12;
    const int M  = B * N;     // 18464
    const int C3 = 3 * C;     // 2304
    const int MB = (M + 127) / 128;   // 145

    short* qkvb   = (short*)d_ws;
    short* attn_o = qkvb + (size_t)M * C3;
    short* xb     = attn_o + (size_t)M * C;
    short* wqkvT  = xb + (size_t)M * C;
    short* wprojT = wqkvT + (size_t)C3 * C;

    dim3 blk(256);
    const long n4 = (long)M * C / 4;
    convert_bf16<<<dim3((n4 + 255) / 256), blk, 0, stream>>>(x, xb, n4);
    transpose_bf16<<<dim3(C3 / 32, C / 32), blk, 0, stream>>>(w_qkv, wqkvT, C, C3);
    transpose_bf16<<<dim3(C / 32, C / 32), blk, 0, stream>>>(w_proj, wprojT, C, C);

    gemm_bf16<short><<<dim3(MB * (C3 / 128)), blk, 0, stream>>>(
        xb, wqkvT, b_qkv, qkvb, M, C3, C, C3 / 128);

    flash_attn<<<dim3(((N + 63) / 64) * H * B), blk, 0, stream>>>(qkvb, scale, attn_o);

    gemm_bf16<float><<<dim3(MB * (C / 128)), blk, 0, stream>>>(
        attn_o, wprojT, b_proj, out, M, C, C, C / 128);
}

// Round 10
// 277.057 us; speedup vs baseline: 1.1557x; 1.0451x over previous
//
#include <hip/hip_runtime.h>
#include <math.h>

#define HD 64
#define KVBLK 64
#define LP 72

typedef __attribute__((ext_vector_type(8))) short short8;
typedef __attribute__((ext_vector_type(4))) short short4v;
typedef __attribute__((ext_vector_type(4))) float f32x4;

__device__ __forceinline__ short f2bf(float f) {
    union { float f; unsigned u; } in;
    in.f = f;
    unsigned r = (in.u + 0x7fff + ((in.u >> 16) & 1)) >> 16;  // RNE
    return (short)r;
}

// ---------------- fp32 -> bf16 convert ----------------
__global__ __launch_bounds__(256) void convert_bf16(const float* __restrict__ in,
                                                    short* __restrict__ out, long n4) {
    long i = blockIdx.x * 256L + threadIdx.x;
    if (i >= n4) return;
    float4 v = reinterpret_cast<const float4*>(in)[i];
    short4v o;
    o[0] = f2bf(v.x); o[1] = f2bf(v.y); o[2] = f2bf(v.z); o[3] = f2bf(v.w);
    reinterpret_cast<short4v*>(out)[i] = o;
}

// ------------- transpose + convert: [K][N] fp32 -> [N][K] bf16 -------------
__global__ __launch_bounds__(256) void transpose_bf16(const float* __restrict__ in,
                                                      short* __restrict__ out, int K, int N) {
    __shared__ float tile[32][33];
    const int n0 = blockIdx.x * 32, k0 = blockIdx.y * 32;
    const int tx = threadIdx.x & 31, ty = threadIdx.x >> 5;
    #pragma unroll
    for (int i = ty; i < 32; i += 8)
        tile[i][tx] = in[(size_t)(k0 + i) * N + n0 + tx];
    __syncthreads();
    #pragma unroll
    for (int i = ty; i < 32; i += 8)
        out[(size_t)(n0 + i) * K + k0 + tx] = f2bf(tile[tx][i]);
}

// ------- V pre-transpose: qkv V-part [b][key][h][d] -> vT[(b*H+h)][d][key640] -------
// Zero-fills keys >= 577 so masked tail contributes exact 0 in PV.
__global__ __launch_bounds__(256) void transpose_v(const short* __restrict__ qkvb,
                                                   short* __restrict__ vT) {
    constexpr int Nn = 577, C3 = 2304, NH = 12, NKP = 640;
    const int bh = blockIdx.x;         // b*12+h
    const int kt = blockIdx.y;         // 32-key tile
    const int b = bh / NH, h = bh % NH;
    const int tid = threadIdx.x;
    __shared__ short tile[64][33];

    const int tk = tid >> 3;           // key-in-tile 0..31
    const int key = kt * 32 + tk;
    const int d0 = (tid & 7) * 8;
    short8 v = {0, 0, 0, 0, 0, 0, 0, 0};
    if (key < Nn)
        v = *reinterpret_cast<const short8*>(
            qkvb + (size_t)(b * Nn + key) * C3 + 1536 + h * 64 + d0);
    #pragma unroll
    for (int i = 0; i < 8; ++i) tile[d0 + i][tk] = v[i];
    __syncthreads();

    const int d = tid >> 2;
    const int kb = (tid & 3) * 8;
    short8 o;
    #pragma unroll
    for (int i = 0; i < 8; ++i) o[i] = tile[d][kb + i];
    *reinterpret_cast<short8*>(vT + (size_t)(bh * 64 + d) * NKP + kt * 32 + kb) = o;
}

// ------- bf16 MFMA GEMM: 128x128, explicit LDS dbuf, ONE barrier per K-step -------
template <typename OutT>
__global__ __launch_bounds__(256) void gemm_bf16(const short* __restrict__ A,
                                                 const short* __restrict__ Bt,
                                                 const float* __restrict__ bias,
                                                 OutT* __restrict__ C,
                                                 int M, int N, int K, int nbn) {
    __shared__ short As[2][128 * 64];
    __shared__ short Bs[2][128 * 64];
    const int tid = threadIdx.x;
    const int w = tid >> 6, lane = tid & 63;
    const int g = lane >> 4, l16 = lane & 15;

    const int nwg = gridDim.x;
    const int q = nwg >> 3, r = nwg & 7;
    const int xcd = blockIdx.x & 7, loc = blockIdx.x >> 3;
    const int wgid = (xcd < r ? xcd * (q + 1) : r * (q + 1) + (xcd - r) * q) + loc;
    const int bm = wgid / nbn, bn = wgid % nbn;
    const int m0 = bm * 128, n0 = bn * 128;
    const int wm = (w >> 1) * 64, wn = (w & 1) * 64;

    f32x4 acc[4][4] = {};

    const int lr = lane >> 3;
    const int lc = (lane & 7) * 8;
    const int NT = K >> 6;

    auto stage = [&](int buf, int k0) {
        #pragma unroll
        for (int t = 0; t < 4; ++t) {
            const int rr = 32 * w + 8 * t + lr;
            long arow = m0 + rr; if (arow > M - 1) arow = M - 1;
            const short* ga = A + arow * K + k0 + lc;
            const short* gb = Bt + (size_t)(n0 + rr) * K + k0 + lc;
            __builtin_amdgcn_global_load_lds(
                (const __attribute__((address_space(1))) unsigned*)ga,
                (__attribute__((address_space(3))) unsigned*)&As[buf][(32 * w + 8 * t) * 64],
                16, 0, 0);
            __builtin_amdgcn_global_load_lds(
                (const __attribute__((address_space(1))) unsigned*)gb,
                (__attribute__((address_space(3))) unsigned*)&Bs[buf][(32 * w + 8 * t) * 64],
                16, 0, 0);
        }
    };

    stage(0, 0);
    __syncthreads();

    for (int kt = 0; kt < NT; ++kt) {
        const int cur = kt & 1;
        if (kt + 1 < NT) stage(cur ^ 1, (kt + 1) * 64);

        #pragma unroll
        for (int ks = 0; ks < 2; ++ks) {
            short8 af[4], bfr[4];
            #pragma unroll
            for (int mi = 0; mi < 4; ++mi)
                af[mi] = *reinterpret_cast<const short8*>(
                    &As[cur][(wm + mi * 16 + l16) * 64 + ks * 32 + g * 8]);
            #pragma unroll
            for (int ni = 0; ni < 4; ++ni)
                bfr[ni] = *reinterpret_cast<const short8*>(
                    &Bs[cur][(wn + ni * 16 + l16) * 64 + ks * 32 + g * 8]);
            __builtin_amdgcn_s_setprio(1);
            #pragma unroll
            for (int mi = 0; mi < 4; ++mi)
                #pragma unroll
                for (int ni = 0; ni < 4; ++ni)
                    acc[mi][ni] = __builtin_amdgcn_mfma_f32_16x16x32_bf16(
                        af[mi], bfr[ni], acc[mi][ni], 0, 0, 0);
            __builtin_amdgcn_s_setprio(0);
        }
        __syncthreads();
    }

    float bv[4];
    #pragma unroll
    for (int ni = 0; ni < 4; ++ni) bv[ni] = bias[n0 + wn + ni * 16 + l16];
    #pragma unroll
    for (int mi = 0; mi < 4; ++mi) {
        #pragma unroll
        for (int rr = 0; rr < 4; ++rr) {
            const int row = m0 + wm + mi * 16 + g * 4 + rr;
            if (row < M) {
                #pragma unroll
                for (int ni = 0; ni < 4; ++ni) {
                    float val = acc[mi][ni][rr] + bv[ni];
                    if constexpr (__is_same(OutT, float))
                        C[(size_t)row * N + n0 + wn + ni * 16 + l16] = val;
                    else
                        C[(size_t)row * N + n0 + wn + ni * 16 + l16] = f2bf(val);
                }
            }
        }
    }
}

// ------- flash attention: swapped-QK^T, both K and V via global_load_lds -------
__global__ __launch_bounds__(256) void flash_attn(const short* __restrict__ qkvb,
                                                  const short* __restrict__ vT,
                                                  const float* __restrict__ scale,
                                                  short* __restrict__ out) {
    constexpr int Nn = 577, Cc = 768, C3 = 2304, NQB = 10, NH = 12, NT = 10, NKP = 640;
    const int bid = blockIdx.x;
    const int swz = (bid & 7) * 480 + (bid >> 3);   // T1: q-blocks of (b,h) share an XCD
    const int q0 = (swz % NQB) * 64;
    const int h  = (swz / NQB) % NH;
    const int b  = swz / (NQB * NH);
    const int qblk = q0 >> 6;

    const int tid  = threadIdx.x;
    const int w    = tid >> 6;
    const int lane = tid & 63;
    const int g    = lane >> 4;
    const int l16  = lane & 15;

    __shared__ alignas(16) short Ks[2][KVBLK * HD];   // XOR-swizzled content, dbuf
    __shared__ alignas(16) short Vts[2][HD * KVBLK];  // V^T[dim][key], XOR-swizzled, dbuf
    __shared__ alignas(16) short Ps[4][16][LP];
    __shared__ float facs[4][16];

    const float sl2 = scale[h] * 1.44269504088896f;
    const float thr = 8.0f / sl2;                      // defer-max threshold in raw units
    const short* base = qkvb + (size_t)b * Nn * C3;
    const short* kglob = base + Cc + h * HD;
    const short* vtb = vT + (size_t)(b * NH + h) * HD * NKP;

    const int qrow = q0 + w * 16 + l16;
    const int qr = qrow < Nn ? qrow : Nn - 1;
    const short* qp = base + (size_t)qr * C3 + h * HD;
    short8 aq[2];
    aq[0] = *reinterpret_cast<const short8*>(qp + 8 * g);
    aq[1] = *reinterpret_cast<const short8*>(qp + 32 + 8 * g);

    f32x4 oacc[4] = {};
    float mrun = -INFINITY, m2 = -INFINITY, lrun = 0.f;

    const int kst_row = lane >> 3;
    const int kst_dblk = (lane & 7) ^ (lane >> 3);

    auto stageK = [&](int bufi, int kv0) {
        #pragma unroll
        for (int t = 0; t < 2; ++t) {
            const int i = 2 * w + t;
            int kr = kv0 + 8 * i + kst_row;
            if (kr > Nn - 1) kr = Nn - 1;
            const short* src = kglob + (size_t)kr * C3 + kst_dblk * 8;
            __builtin_amdgcn_global_load_lds(
                (const __attribute__((address_space(1))) unsigned*)src,
                (__attribute__((address_space(3))) unsigned*)&Ks[bufi][i * 512],
                16, 0, 0);
        }
    };
    auto stageV = [&](int bufi, int kv0) {
        #pragma unroll
        for (int t = 0; t < 2; ++t) {
            const int i = 2 * w + t;
            const int r = 8 * i + kst_row;                 // dim-row 0..63
            const int kb = (lane & 7) ^ (r & 7);           // pre-swizzled key block
            const short* src = vtb + (size_t)r * NKP + kv0 + kb * 8;
            __builtin_amdgcn_global_load_lds(
                (const __attribute__((address_space(1))) unsigned*)src,
                (__attribute__((address_space(3))) unsigned*)&Vts[bufi][i * 512],
                16, 0, 0);
        }
    };

    stageK(0, 0);
    stageV(0, 0);
    __syncthreads();

    for (int t = 0; t < NT; ++t) {
        const int cur = t & 1, nxt = cur ^ 1;
        const int kv0 = t * KVBLK;
        const bool more = (t + 1 < NT);
        if (more) { stageK(nxt, kv0 + KVBLK); stageV(nxt, kv0 + KVBLK); }

        // ---- S^T = K @ Q^T ----
        f32x4 sacc[4] = {};
        __builtin_amdgcn_s_setprio(1);
        #pragma unroll
        for (int f = 0; f < 4; ++f) {
            #pragma unroll
            for (int c = 0; c < 2; ++c) {
                const int slot = (4 * c + g) ^ (l16 & 7);
                short8 ak = *reinterpret_cast<const short8*>(
                    &Ks[cur][(16 * f + l16) * 64 + slot * 8]);
                sacc[f] = __builtin_amdgcn_mfma_f32_16x16x32_bf16(ak, aq[c], sacc[f], 0, 0, 0);
            }
        }
        __builtin_amdgcn_s_setprio(0);

        // ---- raw scores; mask only on the diag tile and the tail tile ----
        const int ig = q0 + w * 16 + l16;
        float s2[4][4];
        #pragma unroll
        for (int f = 0; f < 4; ++f)
            #pragma unroll
            for (int r = 0; r < 4; ++r)
                s2[f][r] = sacc[f][r];
        if (t == qblk || t == NT - 1) {
            #pragma unroll
            for (int f = 0; f < 4; ++f)
                #pragma unroll
                for (int r = 0; r < 4; ++r) {
                    const int jg = kv0 + 16 * f + 4 * g + r;
                    if (jg >= Nn || (jg == ig && ig >= 1)) s2[f][r] = -INFINITY;
                }
        }

        float mx = s2[0][0];
        #pragma unroll
        for (int f = 0; f < 4; ++f)
            #pragma unroll
            for (int r = 0; r < 4; ++r)
                if (f + r) mx = fmaxf(mx, s2[f][r]);
        mx = fmaxf(mx, __shfl_xor(mx, 16, 64));
        mx = fmaxf(mx, __shfl_xor(mx, 32, 64));

        // ---- T13 defer-max (raw units) ----
        if (__any(mx > mrun + thr)) {
            const float mnew = fmaxf(mrun, mx);
            const float m2new = mnew * sl2;
            const float fac = __builtin_amdgcn_exp2f(m2 - m2new);
            mrun = mnew; m2 = m2new;
            lrun *= fac;
            if (lane < 16) facs[w][lane] = fac;
            asm volatile("s_waitcnt lgkmcnt(0)" ::: "memory");
            #pragma unroll
            for (int r = 0; r < 4; ++r) {
                const float fr = facs[w][4 * g + r];
                #pragma unroll
                for (int df = 0; df < 4; ++df) oacc[df][r] *= fr;
            }
        }

        float sum = 0.f;
        #pragma unroll
        for (int f = 0; f < 4; ++f)
            #pragma unroll
            for (int r = 0; r < 4; ++r) {
                float p = __builtin_amdgcn_exp2f(fmaf(s2[f][r], sl2, -m2));
                s2[f][r] = p;
                sum += p;
            }
        sum += __shfl_xor(sum, 16, 64);
        sum += __shfl_xor(sum, 32, 64);
        lrun += sum;

        // ---- P pack ----
        #pragma unroll
        for (int f = 0; f < 4; ++f) {
            unsigned plo, phi;
            asm("v_cvt_pk_bf16_f32 %0, %1, %2" : "=v"(plo) : "v"(s2[f][0]), "v"(s2[f][1]));
            asm("v_cvt_pk_bf16_f32 %0, %1, %2" : "=v"(phi) : "v"(s2[f][2]), "v"(s2[f][3]));
            unsigned* dst = reinterpret_cast<unsigned*>(&Ps[w][l16][16 * f + 4 * g]);
            dst[0] = plo; dst[1] = phi;
        }
        asm volatile("s_waitcnt lgkmcnt(0)" ::: "memory");

        // ---- O += P @ V ----
        __builtin_amdgcn_s_setprio(1);
        #pragma unroll
        for (int c = 0; c < 2; ++c) {
            short8 pa = *reinterpret_cast<const short8*>(&Ps[w][l16][32 * c + 8 * g]);
            #pragma unroll
            for (int df = 0; df < 4; ++df) {
                const int slot = (4 * c + g) ^ (l16 & 7);
                short8 bv = *reinterpret_cast<const short8*>(
                    &Vts[cur][(16 * df + l16) * 64 + slot * 8]);
                oacc[df] = __builtin_amdgcn_mfma_f32_16x16x32_bf16(pa, bv, oacc[df], 0, 0, 0);
            }
        }
        __builtin_amdgcn_s_setprio(0);
        __syncthreads();   // drains staged K/V for nxt, P-writes retire
    }

    if (lane < 16) facs[w][lane] = lrun;
    asm volatile("s_waitcnt lgkmcnt(0)" ::: "memory");
    #pragma unroll
    for (int r = 0; r < 4; ++r) {
        const int og = q0 + w * 16 + g * 4 + r;
        if (og < Nn) {
            const float inv = 1.f / facs[w][4 * g + r];
            #pragma unroll
            for (int df = 0; df < 4; ++df)
                out[(size_t)(b * Nn + og) * Cc + h * HD + 16 * df + l16] =
                    f2bf(oacc[df][r] * inv);
        }
    }
}

extern "C" void kernel_launch(void* const* d_in, const int* in_sizes, int n_in,
                              void* d_out, int out_size, void* d_ws, size_t ws_size,
                              hipStream_t stream) {
    const float* x      = (const float*)d_in[0];
    const float* w_qkv  = (const float*)d_in[1];
    const float* b_qkv  = (const float*)d_in[2];
    const float* scale  = (const float*)d_in[3];
    const float* w_proj = (const float*)d_in[4];
    const float* b_proj = (const float*)d_in[5];
    float* out = (float*)d_out;

    const int B = 32, N = 577, C = 768, H = 12;
    const int M  = B * N;     // 18464
    const int C3 = 3 * C;     // 2304
    const int MB = (M + 127) / 128;   // 145

    short* qkvb   = (short*)d_ws;                        // M x 3C
    short* attn_o = qkvb + (size_t)M * C3;               // M x C
    short* xb     = attn_o + (size_t)M * C;              // M x C
    short* wqkvT  = xb + (size_t)M * C;                  // 3C x C
    short* wprojT = wqkvT + (size_t)C3 * C;              // C x C
    short* vT     = wprojT + (size_t)C * C;              // B*H x 64 x 640

    dim3 blk(256);
    const long n4 = (long)M * C / 4;
    convert_bf16<<<dim3((n4 + 255) / 256), blk, 0, stream>>>(x, xb, n4);
    transpose_bf16<<<dim3(C3 / 32, C / 32), blk, 0, stream>>>(w_qkv, wqkvT, C, C3);
    transpose_bf16<<<dim3(C / 32, C / 32), blk, 0, stream>>>(w_proj, wprojT, C, C);

    gemm_bf16<short><<<dim3(MB * (C3 / 128)), blk, 0, stream>>>(
        xb, wqkvT, b_qkv, qkvb, M, C3, C, C3 / 128);

    transpose_v<<<dim3(B * H, 20), blk, 0, stream>>>(qkvb, vT);

    flash_attn<<<dim3(((N + 63) / 64) * H * B), blk, 0, stream>>>(qkvb, vT, scale, attn_o);

    gemm_bf16<float><<<dim3(MB * (C / 128)), blk, 0, stream>>>(
        attn_o, wprojT, b_proj, out, M, C, C, C / 128);
}

// Round 11
// 257.053 us; speedup vs baseline: 1.2456x; 1.0778x over previous
//
#include <hip/hip_runtime.h>
#include <math.h>

#define HD 64
#define KVBLK 64
#define LP 72

typedef __attribute__((ext_vector_type(8))) short short8;
typedef __attribute__((ext_vector_type(4))) short short4v;
typedef __attribute__((ext_vector_type(4))) float f32x4;

__device__ __forceinline__ short f2bf(float f) {
    union { float f; unsigned u; } in;
    in.f = f;
    unsigned r = (in.u + 0x7fff + ((in.u >> 16) & 1)) >> 16;  // RNE
    return (short)r;
}

// ---------------- fp32 -> bf16 convert ----------------
__global__ __launch_bounds__(256) void convert_bf16(const float* __restrict__ in,
                                                    short* __restrict__ out, long n4) {
    long i = blockIdx.x * 256L + threadIdx.x;
    if (i >= n4) return;
    float4 v = reinterpret_cast<const float4*>(in)[i];
    short4v o;
    o[0] = f2bf(v.x); o[1] = f2bf(v.y); o[2] = f2bf(v.z); o[3] = f2bf(v.w);
    reinterpret_cast<short4v*>(out)[i] = o;
}

// ------------- transpose + convert: [K][N] fp32 -> [N][K] bf16 -------------
__global__ __launch_bounds__(256) void transpose_bf16(const float* __restrict__ in,
                                                      short* __restrict__ out, int K, int N) {
    __shared__ float tile[32][33];
    const int n0 = blockIdx.x * 32, k0 = blockIdx.y * 32;
    const int tx = threadIdx.x & 31, ty = threadIdx.x >> 5;
    #pragma unroll
    for (int i = ty; i < 32; i += 8)
        tile[i][tx] = in[(size_t)(k0 + i) * N + n0 + tx];
    __syncthreads();
    #pragma unroll
    for (int i = ty; i < 32; i += 8)
        out[(size_t)(n0 + i) * K + k0 + tx] = f2bf(tile[tx][i]);
}

// ------- V pre-transpose: qkv V-part [b][key][h][d] -> vT[(b*H+h)][d][key640] -------
__global__ __launch_bounds__(256) void transpose_v(const short* __restrict__ qkvb,
                                                   short* __restrict__ vT) {
    constexpr int Nn = 577, C3 = 2304, NH = 12, NKP = 640;
    const int bh = blockIdx.x;
    const int kt = blockIdx.y;
    const int b = bh / NH, h = bh % NH;
    const int tid = threadIdx.x;
    __shared__ short tile[64][33];

    const int tk = tid >> 3;
    const int key = kt * 32 + tk;
    const int d0 = (tid & 7) * 8;
    short8 v = {0, 0, 0, 0, 0, 0, 0, 0};
    if (key < Nn)
        v = *reinterpret_cast<const short8*>(
            qkvb + (size_t)(b * Nn + key) * C3 + 1536 + h * 64 + d0);
    #pragma unroll
    for (int i = 0; i < 8; ++i) tile[d0 + i][tk] = v[i];
    __syncthreads();

    const int d = tid >> 2;
    const int kb = (tid & 3) * 8;
    short8 o;
    #pragma unroll
    for (int i = 0; i < 8; ++i) o[i] = tile[d][kb + i];
    *reinterpret_cast<short8*>(vT + (size_t)(bh * 64 + d) * NKP + kt * 32 + kb) = o;
}

// ------- bf16 MFMA GEMM: 128x128, LDS dbuf, ONE barrier/K-step, T2 XOR swizzle -------
// LDS tile [128][64] bf16; staged with source col-block cb = (lane&7)^lr (rule 21),
// read with slot = (4ks+g)^(row&7) -> all 32 banks covered, 2-way (free) aliasing.
template <typename OutT>
__global__ __launch_bounds__(256) void gemm_bf16(const short* __restrict__ A,
                                                 const short* __restrict__ Bt,
                                                 const float* __restrict__ bias,
                                                 OutT* __restrict__ C,
                                                 int M, int N, int K, int nbn) {
    __shared__ short As[2][128 * 64];
    __shared__ short Bs[2][128 * 64];
    const int tid = threadIdx.x;
    const int w = tid >> 6, lane = tid & 63;
    const int g = lane >> 4, l16 = lane & 15;

    // bijective XCD swizzle (m204), bm-major: each XCD owns contiguous row-bands
    const int nwg = gridDim.x;
    const int q = nwg >> 3, r = nwg & 7;
    const int xcd = blockIdx.x & 7, loc = blockIdx.x >> 3;
    const int wgid = (xcd < r ? xcd * (q + 1) : r * (q + 1) + (xcd - r) * q) + loc;
    const int bm = wgid / nbn, bn = wgid % nbn;
    const int m0 = bm * 128, n0 = bn * 128;
    const int wm = (w >> 1) * 64, wn = (w & 1) * 64;

    f32x4 acc[4][4] = {};

    const int lr = lane >> 3;                    // row within 8-row chunk
    const int cb = (lane & 7) ^ lr;              // pre-swizzled source col block (T2)
    const int NT = K >> 6;

    auto stage = [&](int buf, int k0) {
        #pragma unroll
        for (int t = 0; t < 4; ++t) {
            const int rr = 32 * w + 8 * t + lr;
            long arow = m0 + rr; if (arow > M - 1) arow = M - 1;
            const short* ga = A + arow * K + k0 + cb * 8;
            const short* gb = Bt + (size_t)(n0 + rr) * K + k0 + cb * 8;
            __builtin_amdgcn_global_load_lds(
                (const __attribute__((address_space(1))) unsigned*)ga,
                (__attribute__((address_space(3))) unsigned*)&As[buf][(32 * w + 8 * t) * 64],
                16, 0, 0);
            __builtin_amdgcn_global_load_lds(
                (const __attribute__((address_space(1))) unsigned*)gb,
                (__attribute__((address_space(3))) unsigned*)&Bs[buf][(32 * w + 8 * t) * 64],
                16, 0, 0);
        }
    };

    stage(0, 0);
    __syncthreads();

    const int rxor = l16 & 7;   // row&7 for all fragment rows this lane reads
    for (int kt = 0; kt < NT; ++kt) {
        const int cur = kt & 1;
        if (kt + 1 < NT) stage(cur ^ 1, (kt + 1) * 64);

        #pragma unroll
        for (int ks = 0; ks < 2; ++ks) {
            const int slot = ((ks * 4 + g) ^ rxor) * 8;
            short8 af[4], bfr[4];
            #pragma unroll
            for (int mi = 0; mi < 4; ++mi)
                af[mi] = *reinterpret_cast<const short8*>(
                    &As[cur][(wm + mi * 16 + l16) * 64 + slot]);
            #pragma unroll
            for (int ni = 0; ni < 4; ++ni)
                bfr[ni] = *reinterpret_cast<const short8*>(
                    &Bs[cur][(wn + ni * 16 + l16) * 64 + slot]);
            __builtin_amdgcn_s_setprio(1);
            #pragma unroll
            for (int mi = 0; mi < 4; ++mi)
                #pragma unroll
                for (int ni = 0; ni < 4; ++ni)
                    acc[mi][ni] = __builtin_amdgcn_mfma_f32_16x16x32_bf16(
                        af[mi], bfr[ni], acc[mi][ni], 0, 0, 0);
            __builtin_amdgcn_s_setprio(0);
        }
        __syncthreads();
    }

    float bv[4];
    #pragma unroll
    for (int ni = 0; ni < 4; ++ni) bv[ni] = bias[n0 + wn + ni * 16 + l16];
    #pragma unroll
    for (int mi = 0; mi < 4; ++mi) {
        #pragma unroll
        for (int rr = 0; rr < 4; ++rr) {
            const int row = m0 + wm + mi * 16 + g * 4 + rr;
            if (row < M) {
                #pragma unroll
                for (int ni = 0; ni < 4; ++ni) {
                    float val = acc[mi][ni][rr] + bv[ni];
                    if constexpr (__is_same(OutT, float))
                        C[(size_t)row * N + n0 + wn + ni * 16 + l16] = val;
                    else
                        C[(size_t)row * N + n0 + wn + ni * 16 + l16] = f2bf(val);
                }
            }
        }
    }
}

// ------- flash attention: swapped-QK^T, both K and V via global_load_lds -------
__global__ __launch_bounds__(256) void flash_attn(const short* __restrict__ qkvb,
                                                  const short* __restrict__ vT,
                                                  const float* __restrict__ scale,
                                                  short* __restrict__ out) {
    constexpr int Nn = 577, Cc = 768, C3 = 2304, NQB = 10, NH = 12, NT = 10, NKP = 640;
    const int bid = blockIdx.x;
    const int swz = (bid & 7) * 480 + (bid >> 3);
    const int q0 = (swz % NQB) * 64;
    const int h  = (swz / NQB) % NH;
    const int b  = swz / (NQB * NH);
    const int qblk = q0 >> 6;

    const int tid  = threadIdx.x;
    const int w    = tid >> 6;
    const int lane = tid & 63;
    const int g    = lane >> 4;
    const int l16  = lane & 15;

    __shared__ alignas(16) short Ks[2][KVBLK * HD];
    __shared__ alignas(16) short Vts[2][HD * KVBLK];
    __shared__ alignas(16) short Ps[4][16][LP];
    __shared__ float facs[4][16];

    const float sl2 = scale[h] * 1.44269504088896f;
    const float thr = 8.0f / sl2;
    const short* base = qkvb + (size_t)b * Nn * C3;
    const short* kglob = base + Cc + h * HD;
    const short* vtb = vT + (size_t)(b * NH + h) * HD * NKP;

    const int qrow = q0 + w * 16 + l16;
    const int qr = qrow < Nn ? qrow : Nn - 1;
    const short* qp = base + (size_t)qr * C3 + h * HD;
    short8 aq[2];
    aq[0] = *reinterpret_cast<const short8*>(qp + 8 * g);
    aq[1] = *reinterpret_cast<const short8*>(qp + 32 + 8 * g);

    f32x4 oacc[4] = {};
    float mrun = -INFINITY, m2 = -INFINITY, lrun = 0.f;

    const int kst_row = lane >> 3;
    const int kst_dblk = (lane & 7) ^ (lane >> 3);

    auto stageK = [&](int bufi, int kv0) {
        #pragma unroll
        for (int t = 0; t < 2; ++t) {
            const int i = 2 * w + t;
            int kr = kv0 + 8 * i + kst_row;
            if (kr > Nn - 1) kr = Nn - 1;
            const short* src = kglob + (size_t)kr * C3 + kst_dblk * 8;
            __builtin_amdgcn_global_load_lds(
                (const __attribute__((address_space(1))) unsigned*)src,
                (__attribute__((address_space(3))) unsigned*)&Ks[bufi][i * 512],
                16, 0, 0);
        }
    };
    auto stageV = [&](int bufi, int kv0) {
        #pragma unroll
        for (int t = 0; t < 2; ++t) {
            const int i = 2 * w + t;
            const int r = 8 * i + kst_row;
            const int kb = (lane & 7) ^ (r & 7);
            const short* src = vtb + (size_t)r * NKP + kv0 + kb * 8;
            __builtin_amdgcn_global_load_lds(
                (const __attribute__((address_space(1))) unsigned*)src,
                (__attribute__((address_space(3))) unsigned*)&Vts[bufi][i * 512],
                16, 0, 0);
        }
    };

    stageK(0, 0);
    stageV(0, 0);
    __syncthreads();

    for (int t = 0; t < NT; ++t) {
        const int cur = t & 1, nxt = cur ^ 1;
        const int kv0 = t * KVBLK;
        const bool more = (t + 1 < NT);
        if (more) { stageK(nxt, kv0 + KVBLK); stageV(nxt, kv0 + KVBLK); }

        f32x4 sacc[4] = {};
        __builtin_amdgcn_s_setprio(1);
        #pragma unroll
        for (int f = 0; f < 4; ++f) {
            #pragma unroll
            for (int c = 0; c < 2; ++c) {
                const int slot = (4 * c + g) ^ (l16 & 7);
                short8 ak = *reinterpret_cast<const short8*>(
                    &Ks[cur][(16 * f + l16) * 64 + slot * 8]);
                sacc[f] = __builtin_amdgcn_mfma_f32_16x16x32_bf16(ak, aq[c], sacc[f], 0, 0, 0);
            }
        }
        __builtin_amdgcn_s_setprio(0);

        const int ig = q0 + w * 16 + l16;
        float s2[4][4];
        #pragma unroll
        for (int f = 0; f < 4; ++f)
            #pragma unroll
            for (int r = 0; r < 4; ++r)
                s2[f][r] = sacc[f][r];
        if (t == qblk || t == NT - 1) {
            #pragma unroll
            for (int f = 0; f < 4; ++f)
                #pragma unroll
                for (int r = 0; r < 4; ++r) {
                    const int jg = kv0 + 16 * f + 4 * g + r;
                    if (jg >= Nn || (jg == ig && ig >= 1)) s2[f][r] = -INFINITY;
                }
        }

        float mx = s2[0][0];
        #pragma unroll
        for (int f = 0; f < 4; ++f)
            #pragma unroll
            for (int r = 0; r < 4; ++r)
                if (f + r) mx = fmaxf(mx, s2[f][r]);
        mx = fmaxf(mx, __shfl_xor(mx, 16, 64));
        mx = fmaxf(mx, __shfl_xor(mx, 32, 64));

        if (__any(mx > mrun + thr)) {
            const float mnew = fmaxf(mrun, mx);
            const float m2new = mnew * sl2;
            const float fac = __builtin_amdgcn_exp2f(m2 - m2new);
            mrun = mnew; m2 = m2new;
            lrun *= fac;
            if (lane < 16) facs[w][lane] = fac;
            asm volatile("s_waitcnt lgkmcnt(0)" ::: "memory");
            #pragma unroll
            for (int r = 0; r < 4; ++r) {
                const float fr = facs[w][4 * g + r];
                #pragma unroll
                for (int df = 0; df < 4; ++df) oacc[df][r] *= fr;
            }
        }

        float sum = 0.f;
        #pragma unroll
        for (int f = 0; f < 4; ++f)
            #pragma unroll
            for (int r = 0; r < 4; ++r) {
                float p = __builtin_amdgcn_exp2f(fmaf(s2[f][r], sl2, -m2));
                s2[f][r] = p;
                sum += p;
            }
        sum += __shfl_xor(sum, 16, 64);
        sum += __shfl_xor(sum, 32, 64);
        lrun += sum;

        #pragma unroll
        for (int f = 0; f < 4; ++f) {
            unsigned plo, phi;
            asm("v_cvt_pk_bf16_f32 %0, %1, %2" : "=v"(plo) : "v"(s2[f][0]), "v"(s2[f][1]));
            asm("v_cvt_pk_bf16_f32 %0, %1, %2" : "=v"(phi) : "v"(s2[f][2]), "v"(s2[f][3]));
            unsigned* dst = reinterpret_cast<unsigned*>(&Ps[w][l16][16 * f + 4 * g]);
            dst[0] = plo; dst[1] = phi;
        }
        asm volatile("s_waitcnt lgkmcnt(0)" ::: "memory");

        __builtin_amdgcn_s_setprio(1);
        #pragma unroll
        for (int c = 0; c < 2; ++c) {
            short8 pa = *reinterpret_cast<const short8*>(&Ps[w][l16][32 * c + 8 * g]);
            #pragma unroll
            for (int df = 0; df < 4; ++df) {
                const int slot = (4 * c + g) ^ (l16 & 7);
                short8 bv = *reinterpret_cast<const short8*>(
                    &Vts[cur][(16 * df + l16) * 64 + slot * 8]);
                oacc[df] = __builtin_amdgcn_mfma_f32_16x16x32_bf16(pa, bv, oacc[df], 0, 0, 0);
            }
        }
        __builtin_amdgcn_s_setprio(0);
        __syncthreads();
    }

    if (lane < 16) facs[w][lane] = lrun;
    asm volatile("s_waitcnt lgkmcnt(0)" ::: "memory");
    #pragma unroll
    for (int r = 0; r < 4; ++r) {
        const int og = q0 + w * 16 + g * 4 + r;
        if (og < Nn) {
            const float inv = 1.f / facs[w][4 * g + r];
            #pragma unroll
            for (int df = 0; df < 4; ++df)
                out[(size_t)(b * Nn + og) * Cc + h * HD + 16 * df + l16] =
                    f2bf(oacc[df][r] * inv);
        }
    }
}

extern "C" void kernel_launch(void* const* d_in, const int* in_sizes, int n_in,
                              void* d_out, int out_size, void* d_ws, size_t ws_size,
                              hipStream_t stream) {
    const float* x      = (const float*)d_in[0];
    const float* w_qkv  = (const float*)d_in[1];
    const float* b_qkv  = (const float*)d_in[2];
    const float* scale  = (const float*)d_in[3];
    const float* w_proj = (const float*)d_in[4];
    const float* b_proj = (const float*)d_in[5];
    float* out = (float*)d_out;

    const int B = 32, N = 577, C = 768, H = 12;
    const int M  = B * N;     // 18464
    const int C3 = 3 * C;     // 2304
    const int MB = (M + 127) / 128;   // 145

    short* qkvb   = (short*)d_ws;
    short* attn_o = qkvb + (size_t)M * C3;
    short* xb     = attn_o + (size_t)M * C;
    short* wqkvT  = xb + (size_t)M * C;
    short* wprojT = wqkvT + (size_t)C3 * C;
    short* vT     = wprojT + (size_t)C * C;

    dim3 blk(256);
    const long n4 = (long)M * C / 4;
    convert_bf16<<<dim3((n4 + 255) / 256), blk, 0, stream>>>(x, xb, n4);
    transpose_bf16<<<dim3(C3 / 32, C / 32), blk, 0, stream>>>(w_qkv, wqkvT, C, C3);
    transpose_bf16<<<dim3(C / 32, C / 32), blk, 0, stream>>>(w_proj, wprojT, C, C);

    gemm_bf16<short><<<dim3(MB * (C3 / 128)), blk, 0, stream>>>(
        xb, wqkvT, b_qkv, qkvb, M, C3, C, C3 / 128);

    transpose_v<<<dim3(B * H, 20), blk, 0, stream>>>(qkvb, vT);

    flash_attn<<<dim3(((N + 63) / 64) * H * B), blk, 0, stream>>>(qkvb, vT, scale, attn_o);

    gemm_bf16<float><<<dim3(MB * (C / 128)), blk, 0, stream>>>(
        attn_o, wprojT, b_proj, out, M, C, C, C / 128);
}